// Round 4
// baseline (726.150 us; speedup 1.0000x reference)
//
#include <hip/hip_runtime.h>

// ============================================================================
// GPT block: LN1 -> QKV GEMM -> causal attention -> proj(+res) -> LN2 ->
//            FC+GELU -> FC2(+res).  FP32 I/O; bf16 MFMA internals, fp32 accum.
// B=16 T=1024 C=768 H=8 D=96.
//
// Workspace layout (bytes), total 114,819,072 (proven):
//   [0         , 3,538,944 )  attn_wT [2304][768] bf16
//   [3,538,944 , 4,718,592 )  proj_wT [768][768]  bf16
//   [4,718,592 , 9,437,184 )  fc_wT   [3072][768] bf16
//   [9,437,184 , 14,155,776)  fc2_wT  [768][3072] bf16
//   [14,155,776, 39,321,600)  hbuf    [16384][768] bf16 (h / attn_out / h2)
//   [39,321,600, 114,819,072) qkv     [16384][2304] bf16  (live until attn)
//   [39,321,600, 64,487,424 ) x1      [16384][768] bf16   (alias, after attn)
//   [64,487,424, 114,819,072) act     [8192][3072] bf16   (MLP M/2 chunks)
// ============================================================================

typedef __bf16 bf16;
typedef __bf16 bf16x8 __attribute__((ext_vector_type(8)));
typedef __bf16 bf16x4 __attribute__((ext_vector_type(4)));
typedef __bf16 bf16x2 __attribute__((ext_vector_type(2)));
typedef float f32x4 __attribute__((ext_vector_type(4)));

__device__ __forceinline__ void async_copy16(const void* g, void* l)
{
    __builtin_amdgcn_global_load_lds((__attribute__((address_space(1))) void*)g,
                                     (__attribute__((address_space(3))) void*)l,
                                     16, 0, 0);
}

// ---------------------------------------------------------------------------
// 32x32-tiled transpose + fp32->bf16: in[R][C] f32 -> out[C][R] bf16.
// ---------------------------------------------------------------------------
__global__ __launch_bounds__(256) void wtrans(const float* __restrict__ in,
                                              bf16* __restrict__ out,
                                              const int R, const int C)
{
    __shared__ float tile[32][33];
    const int c0 = blockIdx.x * 32, r0 = blockIdx.y * 32;
    const int tx = threadIdx.x, ty = threadIdx.y;
#pragma unroll
    for (int i = 0; i < 4; ++i)
        tile[ty + i * 8][tx] = in[(size_t)(r0 + ty + i * 8) * C + c0 + tx];
    __syncthreads();
#pragma unroll
    for (int i = 0; i < 4; ++i)
        out[(size_t)(c0 + ty + i * 8) * R + r0 + tx] = (bf16)tile[tx][ty + i * 8];
}

// ---------------------------------------------------------------------------
// LayerNorm over C=768. One wave per row, 4 rows/block. TIN = float or bf16.
// ---------------------------------------------------------------------------
template <typename TIN>
__global__ __launch_bounds__(256) void ln_kernel(const TIN* __restrict__ x,
                                                 const float* __restrict__ g,
                                                 const float* __restrict__ bb,
                                                 bf16* __restrict__ out)
{
    const int wave = threadIdx.x >> 6, lane = threadIdx.x & 63;
    const size_t row = (size_t)blockIdx.x * 4 + wave;
    const TIN* xr = x + row * 768;
    float v[12];
    float s = 0.f;
#pragma unroll
    for (int c = 0; c < 3; ++c) {
        if constexpr (sizeof(TIN) == 2) {
            const bf16x4 t4 = *(const bf16x4*)(xr + c * 256 + lane * 4);
#pragma unroll
            for (int j = 0; j < 4; ++j) { v[c * 4 + j] = (float)t4[j]; s += v[c * 4 + j]; }
        } else {
            const float4 t4 = *(const float4*)(xr + c * 256 + lane * 4);
            v[c * 4 + 0] = t4.x; v[c * 4 + 1] = t4.y;
            v[c * 4 + 2] = t4.z; v[c * 4 + 3] = t4.w;
            s += t4.x + t4.y + t4.z + t4.w;
        }
    }
#pragma unroll
    for (int off = 32; off >= 1; off >>= 1) s += __shfl_xor(s, off, 64);
    const float mu = s * (1.f / 768.f);
    float q = 0.f;
#pragma unroll
    for (int i = 0; i < 12; ++i) { const float d = v[i] - mu; q += d * d; }
#pragma unroll
    for (int off = 32; off >= 1; off >>= 1) q += __shfl_xor(q, off, 64);
    const float rs = rsqrtf(q * (1.f / 768.f) + 1e-5f);
#pragma unroll
    for (int c = 0; c < 3; ++c) {
        const float4 gv = *(const float4*)(g + c * 256 + lane * 4);
        const float4 bv = *(const float4*)(bb + c * 256 + lane * 4);
        bf16x4 ov;
        ov[0] = (bf16)((v[c * 4 + 0] - mu) * rs * gv.x + bv.x);
        ov[1] = (bf16)((v[c * 4 + 1] - mu) * rs * gv.y + bv.y);
        ov[2] = (bf16)((v[c * 4 + 2] - mu) * rs * gv.z + bv.z);
        ov[3] = (bf16)((v[c * 4 + 3] - mu) * rs * gv.w + bv.w);
        *(bf16x4*)(out + row * 768 + c * 256 + lane * 4) = ov;
    }
}

// ---------------------------------------------------------------------------
// bf16 GEMM: C[M,N] = A[M,K] * Bt[N,K]^T (+ epilogue). BK=64 as two stacked
// BK=32 LDS images; global_load_lds staging; 128xTN tile, 4 waves. K%64==0.
// EPI: 0 bias->bf16 | 1 bias+res(f32)->bf16 | 2 bias+GELU->bf16
//      3 bias+res(bf16)->f32
// ---------------------------------------------------------------------------
template <int EPI, int TN>
__global__ __launch_bounds__(256) void gemm_bt(const bf16* __restrict__ A,
                                               const bf16* __restrict__ Bt,
                                               const float* __restrict__ bias,
                                               const void* __restrict__ res,
                                               void* __restrict__ out,
                                               const int M, const int N, const int K)
{
    constexpr int NT_W = TN / 32;           // nt tiles per wave
    constexpr int NCPB = (TN * 8) / 256;    // B staging copies (4 or 2)
    __shared__ bf16 sA[2 * 128 * 32];       // image ks at sA + ks*4096
    __shared__ bf16 sB[2 * TN * 32];        // image ks at sB + ks*TN*32
    const int t = threadIdx.x;
    const int wave = t >> 6, lane = t & 63;
    const int quad = lane >> 4, l16 = lane & 15;
    const int bm0 = blockIdx.y * 128, bn0 = blockIdx.x * TN;
    const int wm = (wave >> 1) * 64, wn = (wave & 1) * (TN / 2);

    const f32x4 z4 = {0.f, 0.f, 0.f, 0.f};
    f32x4 acc[4][NT_W];
#pragma unroll
    for (int i = 0; i < 4; ++i)
#pragma unroll
        for (int j = 0; j < NT_W; ++j) acc[i][j] = z4;

    const bf16* gAp[4]; bf16* lAp[4];
#pragma unroll
    for (int c = 0; c < 4; ++c) {
        const int j = c * 256 + t;
        const int img = j >> 9, r = (j >> 2) & 127, k8 = j & 3;
        gAp[c] = A + (size_t)(bm0 + r) * K + img * 32 + k8 * 8;
        lAp[c] = sA + j * 8;
    }
    const bf16* gBp[NCPB]; bf16* lBp[NCPB];
#pragma unroll
    for (int c = 0; c < NCPB; ++c) {
        const int j = c * 256 + t;
        const int img = j / (TN * 4), r = (j % (TN * 4)) >> 2, k8 = j & 3;
        gBp[c] = Bt + (size_t)(bn0 + r) * K + img * 32 + k8 * 8;
        lBp[c] = sB + j * 8;
    }

    for (int kt = 0; kt < K; kt += 64) {
        __syncthreads();
#pragma unroll
        for (int c = 0; c < 4; ++c) async_copy16(gAp[c] + kt, lAp[c]);
#pragma unroll
        for (int c = 0; c < NCPB; ++c) async_copy16(gBp[c] + kt, lBp[c]);
        __syncthreads();

#pragma unroll
        for (int ks = 0; ks < 2; ++ks) {
            bf16x8 af[4], bfm[NT_W];
#pragma unroll
            for (int mt = 0; mt < 4; ++mt)
                af[mt] = *(const bf16x8*)(sA + ks * 4096 +
                                          (wm + mt * 16 + l16) * 32 + quad * 8);
#pragma unroll
            for (int nt = 0; nt < NT_W; ++nt)
                bfm[nt] = *(const bf16x8*)(sB + ks * (TN * 32) +
                                           (wn + nt * 16 + l16) * 32 + quad * 8);
#pragma unroll
            for (int mt = 0; mt < 4; ++mt)
#pragma unroll
                for (int nt = 0; nt < NT_W; ++nt)
                    acc[mt][nt] = __builtin_amdgcn_mfma_f32_16x16x32_bf16(
                        af[mt], bfm[nt], acc[mt][nt], 0, 0, 0);
        }
    }

    // C/D layout: row = quad*4 + reg, col = l16 (per 16x16 tile).
    const int rb = bm0 + wm + quad * 4;
    const int cb = bn0 + wn + l16;
#pragma unroll
    for (int mt = 0; mt < 4; ++mt) {
#pragma unroll
        for (int nt = 0; nt < NT_W; ++nt) {
            const int col = cb + nt * 16;
            const float bv = bias[col];
#pragma unroll
            for (int reg = 0; reg < 4; ++reg) {
                const size_t idx = (size_t)(rb + mt * 16 + reg) * N + col;
                float v = acc[mt][nt][reg] + bv;
                if constexpr (EPI == 1) {
                    ((bf16*)out)[idx] = (bf16)(v + ((const float*)res)[idx]);
                } else if constexpr (EPI == 2) {
                    const float u = v;
                    const float a2 = 1.5957691216057308f *
                                     (u + 0.044715f * u * u * u);
                    v = u / (1.f + __expf(-a2));
                    ((bf16*)out)[idx] = (bf16)v;
                } else if constexpr (EPI == 3) {
                    ((float*)out)[idx] = v + (float)((const bf16*)res)[idx];
                } else {
                    ((bf16*)out)[idx] = (bf16)v;
                }
            }
        }
    }
}

// ---------------------------------------------------------------------------
// Causal flash attention v7 = v6 structure + LDS-pipe reduction.
// Merged pair (qA, qB=15-qA share each staged tile). 4 waves/block,
// grid (128, 8): XCD = bh%8 -> all 8 q-blocks of one (b,h) share one XCD L2
// (v6-proven: FETCH 166->75 MB).
// v7 changes (theory: LDS pipe ~46% busy was the hidden bottleneck):
//  1. sV stride 72 -> 68 els. 72 els = 36 dw == 4 (mod 32): PV's V-reads hit
//     8 bank groups with 64 lanes -> multi-way conflict on all 12 reads per
//     process (the 7.1M SQ_LDS_BANK_CONFLICT). 68 els = 34 dw == 2 (mod 32)
//     -> 16 groups, <=2-way, free.
//  2. psum butterfly (16 ds_swizzle + 32 VALU per process) replaced by MFMA
//     row-sum: o7 += P @ ones. MFMA pipe is at 9% -- free. Also makes
//     numerator/denominator consistently sum bf16(p).
//  3. K staged via global_load_lds into linear sK[64][128] with XOR chunk
//     swizzle (pos = dc ^ (row&7), 16B chunks): removes 3 global->reg loads
//     + 3 ds_write_b128 per thread per tile. Source pre-swizzled, read
//     applies same XOR (both-sides-or-neither). Pad chunks load garbage from
//     within the same qkv row (safe, never read back).
// Fixed-reference softmax: p = exp(min(s,30)); final /rowsum. Causal mask on
// diagonal tile only (block-uniform).
// LDS: sK 16384 + sV 13056 + sP 9728 = 39168 B -> 4 blocks/CU preserved.
// Do NOT add register state beyond ~112 VGPR (v4/v5: spills past 128).
// ---------------------------------------------------------------------------
__global__ __launch_bounds__(256) void attn_kernel(const bf16* __restrict__ qkv,
                                                   bf16* __restrict__ aout)
{
    constexpr int T = 1024, C3 = 2304, HD = 96, CC = 768;
    __shared__ bf16 sK[64 * 128];     // 16 chunks of 16B per row, XOR-swizzled
    __shared__ bf16 sV[96 * 68];      // V transposed [d][key], stride 68
    __shared__ bf16 sP[4][16 * 76];
    const int tid = threadIdx.x;
    const int wave = tid >> 6, lane = tid & 63;
    const int quad = lane >> 4, l16 = lane & 15;
    const int bh = blockIdx.x, b = bh >> 3, h = bh & 7;
    const float scale = 0.10206207261596575f;  // 1/sqrt(96)

    const int qAi = blockIdx.y;       // 0..7
    const int qBi = 15 - qAi;         // 8..15
    const int q0A = qAi * 64 + wave * 16;
    const int q0B = qBi * 64 + wave * 16;

    const bf16* kgbase = qkv + (size_t)b * T * C3 + CC + h * HD;      // K
    const bf16* vgbase = qkv + (size_t)b * T * C3 + 2 * CC + h * HD;  // V
    bf16* sPw = &sP[wave][0];

    // K staging: 1024 16B-chunks, 4 per thread. Position chunk (row,pos)
    // holds data chunk dc = pos ^ (row&7). dc in 12..15 loads garbage from
    // within the same qkv row (CC + h*96 + dc*8 + 8 <= 1568 < 2304: safe).
    int kSrc[4]; bf16* kLds[4];
#pragma unroll
    for (int c = 0; c < 4; ++c) {
        const int chunk = c * 256 + tid;
        const int row = chunk >> 4, pos = chunk & 15;
        const int dc = pos ^ (row & 7);
        kSrc[c] = row * C3 + dc * 8;
        kLds[c] = sK + chunk * 8;
    }
    // V staging index precompute (j = c*256 + tid)
    int vKey2[3], vDq[3];
#pragma unroll
    for (int c = 0; c < 3; ++c) {
        const int j = c * 256 + tid;
        vKey2[c] = (j & 31) * 2; vDq[c] = j >> 5;
    }

    // Q A-frags for both tiles: A[m=l16][k=d], d = c*32 + quad*8 + j
    const bf16* qrA = qkv + (size_t)(b * T + q0A + l16) * C3 + h * HD + quad * 8;
    const bf16* qrB = qkv + (size_t)(b * T + q0B + l16) * C3 + h * HD + quad * 8;
    const bf16x8 aQA0 = *(const bf16x8*)(qrA);
    const bf16x8 aQA1 = *(const bf16x8*)(qrA + 32);
    const bf16x8 aQA2 = *(const bf16x8*)(qrA + 64);
    const bf16x8 aQB0 = *(const bf16x8*)(qrB);
    const bf16x8 aQB1 = *(const bf16x8*)(qrB + 32);
    const bf16x8 aQB2 = *(const bf16x8*)(qrB + 64);

    bf16x8 ones;
#pragma unroll
    for (int j = 0; j < 8; ++j) ones[j] = (bf16)1.0f;

    const f32x4 z4 = {0.f, 0.f, 0.f, 0.f};
    f32x4 oA[6], oB[6];
#pragma unroll
    for (int i = 0; i < 6; ++i) { oA[i] = z4; oB[i] = z4; }
    f32x4 o7A = z4, o7B = z4;   // row-sum accumulators (all cols identical)

    // one q-tile update against the staged sK/sV tile
    auto process = [&](const bf16x8& Q0, const bf16x8& Q1, const bf16x8& Q2,
                       f32x4 (&o)[6], f32x4& o7,
                       const int q0, const int kk0, const bool diag) {
        f32x4 s[4];
#pragma unroll
        for (int i = 0; i < 4; ++i) s[i] = z4;
#pragma unroll
        for (int nt = 0; nt < 4; ++nt) {
            const int rr = nt * 16 + l16;
            const bf16* kpr = sK + rr * 128;
            const int rx = rr & 7;
            const bf16x8 b0 = *(const bf16x8*)(kpr + ((quad + 0) ^ rx) * 8);
            const bf16x8 b1 = *(const bf16x8*)(kpr + ((quad + 4) ^ rx) * 8);
            const bf16x8 b2 = *(const bf16x8*)(kpr + ((quad + 8) ^ rx) * 8);
            s[nt] = __builtin_amdgcn_mfma_f32_16x16x32_bf16(Q0, b0, s[nt], 0, 0, 0);
            s[nt] = __builtin_amdgcn_mfma_f32_16x16x32_bf16(Q1, b1, s[nt], 0, 0, 0);
            s[nt] = __builtin_amdgcn_mfma_f32_16x16x32_bf16(Q2, b2, s[nt], 0, 0, 0);
        }

        // mask (diagonal tile only; block-uniform) + exp
#pragma unroll
        for (int nt = 0; nt < 4; ++nt)
#pragma unroll
            for (int reg = 0; reg < 4; ++reg) {
                float v = s[nt][reg] * scale;
                if (diag) {
                    const int qr = q0 + quad * 4 + reg;
                    const int key = kk0 + nt * 16 + l16;
                    v = (key > qr) ? -1e30f : v;
                }
                s[nt][reg] = __expf(fminf(v, 30.f));
            }

        // P: C-layout -> LDS (stride 76) -> A-layout, per-wave region
#pragma unroll
        for (int nt = 0; nt < 4; ++nt)
#pragma unroll
            for (int reg = 0; reg < 4; ++reg)
                sPw[(quad * 4 + reg) * 76 + nt * 16 + l16] = (bf16)s[nt][reg];
        __asm__ volatile("s_waitcnt lgkmcnt(0)" ::: "memory");

        const bf16x8 aP0 = *(const bf16x8*)(sPw + l16 * 76 + quad * 8);
        const bf16x8 aP1 = *(const bf16x8*)(sPw + l16 * 76 + 32 + quad * 8);
        // row-sum via MFMA (B = ones): D[m][*] = sum_k P[m][k]
        o7 = __builtin_amdgcn_mfma_f32_16x16x32_bf16(aP0, ones, o7, 0, 0, 0);
        o7 = __builtin_amdgcn_mfma_f32_16x16x32_bf16(aP1, ones, o7, 0, 0, 0);
#pragma unroll
        for (int dd = 0; dd < 6; ++dd) {
            const bf16* vp = sV + (dd * 16 + l16) * 68 + quad * 8;
            const bf16x8 v0 = *(const bf16x8*)(vp);
            const bf16x8 v1 = *(const bf16x8*)(vp + 32);
            o[dd] = __builtin_amdgcn_mfma_f32_16x16x32_bf16(aP0, v0, o[dd], 0, 0, 0);
            o[dd] = __builtin_amdgcn_mfma_f32_16x16x32_bf16(aP1, v1, o[dd], 0, 0, 0);
        }
    };

    for (int kb = 0; kb <= qBi; ++kb) {
        const int kk0 = kb * 64;

        __syncthreads();  // prior tile's sK/sV reads done
        // ---- stage K tile: async global->LDS, XOR-swizzled chunks ----
#pragma unroll
        for (int c = 0; c < 4; ++c)
            async_copy16(kgbase + (size_t)kk0 * C3 + kSrc[c], kLds[c]);
        // ---- stage V tile: sV[d][key] (packed b32, stride 68) ----
#pragma unroll
        for (int c = 0; c < 3; ++c) {
            const bf16* p0 = vgbase + (size_t)(kk0 + vKey2[c]) * C3 + vDq[c] * 4;
            const bf16x4 va = *(const bf16x4*)p0;
            const bf16x4 vb = *(const bf16x4*)(p0 + C3);
#pragma unroll
            for (int jj = 0; jj < 4; ++jj) {
                bf16x2 pk; pk[0] = va[jj]; pk[1] = vb[jj];
                *(bf16x2*)(sV + (vDq[c] * 4 + jj) * 68 + vKey2[c]) = pk;
            }
        }
        __syncthreads();  // drains vmcnt (K copies) + lgkm (V writes)

        // qB every tile; qA while kb <= qAi (both block-uniform)
        process(aQB0, aQB1, aQB2, oB, o7B, q0B, kk0, kb == qBi);
        if (kb <= qAi)
            process(aQA0, aQA1, aQA2, oA, o7A, q0A, kk0, kb == qAi);
    }

    // ---- write both outputs: aout[b, t, h*96 + d] ----
    bf16* opA = aout + (size_t)(b * T + q0A + quad * 4) * CC + h * HD + l16;
    bf16* opB = aout + (size_t)(b * T + q0B + quad * 4) * CC + h * HD + l16;
#pragma unroll
    for (int reg = 0; reg < 4; ++reg) {
        const float invA = 1.f / o7A[reg];
        const float invB = 1.f / o7B[reg];
#pragma unroll
        for (int dd = 0; dd < 6; ++dd) {
            opA[(size_t)reg * CC + dd * 16] = (bf16)(oA[dd][reg] * invA);
            opB[(size_t)reg * CC + dd * 16] = (bf16)(oB[dd][reg] * invB);
        }
    }
}

// ===========================================================================
extern "C" void kernel_launch(void* const* d_in, const int* in_sizes, int n_in,
                              void* d_out, int out_size, void* d_ws, size_t ws_size,
                              hipStream_t stream)
{
    const float* x      = (const float*)d_in[0];
    const float* ln1_g  = (const float*)d_in[1];
    const float* ln1_b  = (const float*)d_in[2];
    const float* attn_w = (const float*)d_in[3];
    const float* attn_b = (const float*)d_in[4];
    const float* proj_w = (const float*)d_in[5];
    const float* proj_b = (const float*)d_in[6];
    const float* ln2_g  = (const float*)d_in[7];
    const float* ln2_b  = (const float*)d_in[8];
    const float* fc_w   = (const float*)d_in[9];
    const float* fc_b   = (const float*)d_in[10];
    const float* fc2_w  = (const float*)d_in[11];
    const float* fc2_b  = (const float*)d_in[12];

    char* ws = (char*)d_ws;
    bf16*  attn_wT = (bf16*)(ws + 0);
    bf16*  proj_wT = (bf16*)(ws + 3538944);
    bf16*  fc_wT   = (bf16*)(ws + 4718592);
    bf16*  fc2_wT  = (bf16*)(ws + 9437184);
    bf16*  hbuf    = (bf16*)(ws + 14155776);   // h -> attn_out -> h2
    bf16*  qkv     = (bf16*)(ws + 39321600);   // dead after attention
    bf16*  x1      = (bf16*)(ws + 39321600);   // aliases dead qkv
    bf16*  act     = (bf16*)(ws + 64487424);   // [8192][3072] chunk buffer

    const dim3 tb(32, 8);

    wtrans<<<dim3(72, 24), tb, 0, stream>>>(attn_w, attn_wT, 768, 2304);
    wtrans<<<dim3(24, 24), tb, 0, stream>>>(proj_w, proj_wT, 768, 768);
    wtrans<<<dim3(96, 24), tb, 0, stream>>>(fc_w, fc_wT, 768, 3072);
    wtrans<<<dim3(24, 96), tb, 0, stream>>>(fc2_w, fc2_wT, 3072, 768);

    // LN1: x (f32) -> h (bf16)
    ln_kernel<float><<<4096, 256, 0, stream>>>(x, ln1_g, ln1_b, hbuf);

    // QKV GEMM
    gemm_bt<0, 128><<<dim3(18, 128), 256, 0, stream>>>(
        hbuf, attn_wT, attn_b, nullptr, qkv, 16384, 2304, 768);

    // attention -> hbuf (attn_out); merged-pair causal, grid (bh, qA):
    // XCD = bh%8 so all q-blocks of one (b,h) share one XCD's L2.
    attn_kernel<<<dim3(128, 8), 256, 0, stream>>>(qkv, hbuf);

    // proj + residual: x1 (bf16, aliases dead qkv) = attn_out @ proj_w + b + x
    gemm_bt<1, 128><<<dim3(6, 128), 256, 0, stream>>>(
        hbuf, proj_wT, proj_b, x, x1, 16384, 768, 768);

    // LN2: x1 (bf16) -> h2 (bf16, in hbuf)
    ln_kernel<bf16><<<4096, 256, 0, stream>>>(x1, ln2_g, ln2_b, hbuf);

    // MLP in 2 chunks of 8192 rows; fc2 uses TN=64 (768 blocks = 3/CU)
    for (int c = 0; c < 2; ++c) {
        const size_t ro = (size_t)c * 8192;
        gemm_bt<2, 128><<<dim3(24, 64), 256, 0, stream>>>(
            hbuf + ro * 768, fc_wT, fc_b, nullptr, act, 8192, 3072, 768);
        gemm_bt<3, 64><<<dim3(12, 64), 256, 0, stream>>>(
            act, fc2_wT, fc2_b, x1 + ro * 768,
            (float*)d_out + ro * 768, 8192, 768, 3072);
    }
}

// Round 5
// 717.173 us; speedup vs baseline: 1.0125x; 1.0125x over previous
//
#include <hip/hip_runtime.h>

// ============================================================================
// GPT block: LN1 -> QKV GEMM -> causal attention -> proj(+res) -> LN2 ->
//            FC+GELU -> FC2(+res).  FP32 I/O; bf16 MFMA internals, fp32 accum.
// B=16 T=1024 C=768 H=8 D=96.
//
// Workspace layout (bytes), total 114,819,072 (proven):
//   [0         , 3,538,944 )  attn_wT [2304][768] bf16
//   [3,538,944 , 4,718,592 )  proj_wT [768][768]  bf16
//   [4,718,592 , 9,437,184 )  fc_wT   [3072][768] bf16
//   [9,437,184 , 14,155,776)  fc2_wT  [768][3072] bf16
//   [14,155,776, 39,321,600)  hbuf    [16384][768] bf16 (h / attn_out / h2)
//   [39,321,600, 114,819,072) qkv     [16384][2304] bf16  (live until attn)
//   [39,321,600, 64,487,424 ) x1      [16384][768] bf16   (alias, after attn)
//   [64,487,424, 114,819,072) act     [8192][3072] bf16   (MLP M/2 chunks)
// ============================================================================

typedef __bf16 bf16;
typedef __bf16 bf16x8 __attribute__((ext_vector_type(8)));
typedef __bf16 bf16x4 __attribute__((ext_vector_type(4)));
typedef __bf16 bf16x2 __attribute__((ext_vector_type(2)));
typedef float f32x4 __attribute__((ext_vector_type(4)));

__device__ __forceinline__ void async_copy16(const void* g, void* l)
{
    __builtin_amdgcn_global_load_lds((__attribute__((address_space(1))) void*)g,
                                     (__attribute__((address_space(3))) void*)l,
                                     16, 0, 0);
}

// ---------------------------------------------------------------------------
// 32x32-tiled transpose + fp32->bf16: in[R][C] f32 -> out[C][R] bf16.
// ---------------------------------------------------------------------------
__global__ __launch_bounds__(256) void wtrans(const float* __restrict__ in,
                                              bf16* __restrict__ out,
                                              const int R, const int C)
{
    __shared__ float tile[32][33];
    const int c0 = blockIdx.x * 32, r0 = blockIdx.y * 32;
    const int tx = threadIdx.x, ty = threadIdx.y;
#pragma unroll
    for (int i = 0; i < 4; ++i)
        tile[ty + i * 8][tx] = in[(size_t)(r0 + ty + i * 8) * C + c0 + tx];
    __syncthreads();
#pragma unroll
    for (int i = 0; i < 4; ++i)
        out[(size_t)(c0 + ty + i * 8) * R + r0 + tx] = (bf16)tile[tx][ty + i * 8];
}

// ---------------------------------------------------------------------------
// LayerNorm over C=768. One wave per row, 4 rows/block. TIN = float or bf16.
// ---------------------------------------------------------------------------
template <typename TIN>
__global__ __launch_bounds__(256) void ln_kernel(const TIN* __restrict__ x,
                                                 const float* __restrict__ g,
                                                 const float* __restrict__ bb,
                                                 bf16* __restrict__ out)
{
    const int wave = threadIdx.x >> 6, lane = threadIdx.x & 63;
    const size_t row = (size_t)blockIdx.x * 4 + wave;
    const TIN* xr = x + row * 768;
    float v[12];
    float s = 0.f;
#pragma unroll
    for (int c = 0; c < 3; ++c) {
        if constexpr (sizeof(TIN) == 2) {
            const bf16x4 t4 = *(const bf16x4*)(xr + c * 256 + lane * 4);
#pragma unroll
            for (int j = 0; j < 4; ++j) { v[c * 4 + j] = (float)t4[j]; s += v[c * 4 + j]; }
        } else {
            const float4 t4 = *(const float4*)(xr + c * 256 + lane * 4);
            v[c * 4 + 0] = t4.x; v[c * 4 + 1] = t4.y;
            v[c * 4 + 2] = t4.z; v[c * 4 + 3] = t4.w;
            s += t4.x + t4.y + t4.z + t4.w;
        }
    }
#pragma unroll
    for (int off = 32; off >= 1; off >>= 1) s += __shfl_xor(s, off, 64);
    const float mu = s * (1.f / 768.f);
    float q = 0.f;
#pragma unroll
    for (int i = 0; i < 12; ++i) { const float d = v[i] - mu; q += d * d; }
#pragma unroll
    for (int off = 32; off >= 1; off >>= 1) q += __shfl_xor(q, off, 64);
    const float rs = rsqrtf(q * (1.f / 768.f) + 1e-5f);
#pragma unroll
    for (int c = 0; c < 3; ++c) {
        const float4 gv = *(const float4*)(g + c * 256 + lane * 4);
        const float4 bv = *(const float4*)(bb + c * 256 + lane * 4);
        bf16x4 ov;
        ov[0] = (bf16)((v[c * 4 + 0] - mu) * rs * gv.x + bv.x);
        ov[1] = (bf16)((v[c * 4 + 1] - mu) * rs * gv.y + bv.y);
        ov[2] = (bf16)((v[c * 4 + 2] - mu) * rs * gv.z + bv.z);
        ov[3] = (bf16)((v[c * 4 + 3] - mu) * rs * gv.w + bv.w);
        *(bf16x4*)(out + row * 768 + c * 256 + lane * 4) = ov;
    }
}

// ---------------------------------------------------------------------------
// bf16 GEMM: C[M,N] = A[M,K] * Bt[N,K]^T (+ epilogue). BK=64 as two stacked
// BK=32 LDS images; global_load_lds staging; 128xTN tile, 4 waves. K%64==0.
// EPI: 0 bias->bf16 | 1 bias+res(f32)->bf16 | 2 bias+GELU->bf16
//      3 bias+res(bf16)->f32
// ---------------------------------------------------------------------------
template <int EPI, int TN>
__global__ __launch_bounds__(256) void gemm_bt(const bf16* __restrict__ A,
                                               const bf16* __restrict__ Bt,
                                               const float* __restrict__ bias,
                                               const void* __restrict__ res,
                                               void* __restrict__ out,
                                               const int M, const int N, const int K)
{
    constexpr int NT_W = TN / 32;           // nt tiles per wave
    constexpr int NCPB = (TN * 8) / 256;    // B staging copies (4 or 2)
    __shared__ bf16 sA[2 * 128 * 32];       // image ks at sA + ks*4096
    __shared__ bf16 sB[2 * TN * 32];        // image ks at sB + ks*TN*32
    const int t = threadIdx.x;
    const int wave = t >> 6, lane = t & 63;
    const int quad = lane >> 4, l16 = lane & 15;
    const int bm0 = blockIdx.y * 128, bn0 = blockIdx.x * TN;
    const int wm = (wave >> 1) * 64, wn = (wave & 1) * (TN / 2);

    const f32x4 z4 = {0.f, 0.f, 0.f, 0.f};
    f32x4 acc[4][NT_W];
#pragma unroll
    for (int i = 0; i < 4; ++i)
#pragma unroll
        for (int j = 0; j < NT_W; ++j) acc[i][j] = z4;

    const bf16* gAp[4]; bf16* lAp[4];
#pragma unroll
    for (int c = 0; c < 4; ++c) {
        const int j = c * 256 + t;
        const int img = j >> 9, r = (j >> 2) & 127, k8 = j & 3;
        gAp[c] = A + (size_t)(bm0 + r) * K + img * 32 + k8 * 8;
        lAp[c] = sA + j * 8;
    }
    const bf16* gBp[NCPB]; bf16* lBp[NCPB];
#pragma unroll
    for (int c = 0; c < NCPB; ++c) {
        const int j = c * 256 + t;
        const int img = j / (TN * 4), r = (j % (TN * 4)) >> 2, k8 = j & 3;
        gBp[c] = Bt + (size_t)(bn0 + r) * K + img * 32 + k8 * 8;
        lBp[c] = sB + j * 8;
    }

    for (int kt = 0; kt < K; kt += 64) {
        __syncthreads();
#pragma unroll
        for (int c = 0; c < 4; ++c) async_copy16(gAp[c] + kt, lAp[c]);
#pragma unroll
        for (int c = 0; c < NCPB; ++c) async_copy16(gBp[c] + kt, lBp[c]);
        __syncthreads();

#pragma unroll
        for (int ks = 0; ks < 2; ++ks) {
            bf16x8 af[4], bfm[NT_W];
#pragma unroll
            for (int mt = 0; mt < 4; ++mt)
                af[mt] = *(const bf16x8*)(sA + ks * 4096 +
                                          (wm + mt * 16 + l16) * 32 + quad * 8);
#pragma unroll
            for (int nt = 0; nt < NT_W; ++nt)
                bfm[nt] = *(const bf16x8*)(sB + ks * (TN * 32) +
                                           (wn + nt * 16 + l16) * 32 + quad * 8);
#pragma unroll
            for (int mt = 0; mt < 4; ++mt)
#pragma unroll
                for (int nt = 0; nt < NT_W; ++nt)
                    acc[mt][nt] = __builtin_amdgcn_mfma_f32_16x16x32_bf16(
                        af[mt], bfm[nt], acc[mt][nt], 0, 0, 0);
        }
    }

    // C/D layout: row = quad*4 + reg, col = l16 (per 16x16 tile).
    const int rb = bm0 + wm + quad * 4;
    const int cb = bn0 + wn + l16;
#pragma unroll
    for (int mt = 0; mt < 4; ++mt) {
#pragma unroll
        for (int nt = 0; nt < NT_W; ++nt) {
            const int col = cb + nt * 16;
            const float bv = bias[col];
#pragma unroll
            for (int reg = 0; reg < 4; ++reg) {
                const size_t idx = (size_t)(rb + mt * 16 + reg) * N + col;
                float v = acc[mt][nt][reg] + bv;
                if constexpr (EPI == 1) {
                    ((bf16*)out)[idx] = (bf16)(v + ((const float*)res)[idx]);
                } else if constexpr (EPI == 2) {
                    const float u = v;
                    const float a2 = 1.5957691216057308f *
                                     (u + 0.044715f * u * u * u);
                    v = u / (1.f + __expf(-a2));
                    ((bf16*)out)[idx] = (bf16)v;
                } else if constexpr (EPI == 3) {
                    ((float*)out)[idx] = v + (float)((const bf16*)res)[idx];
                } else {
                    ((bf16*)out)[idx] = (bf16)v;
                }
            }
        }
    }
}

// ---------------------------------------------------------------------------
// Causal flash attention v8 = v6 structure + the two v7-proven LDS wins,
// WITHOUT v7's K global_load_lds staging (that pinned the staging loads
// between the barriers -> exposed L2 latency every tile -> +50us. Reg-based
// staging lets the loads pipeline ahead of the ds_writes; keep it).
// Merged pair (qA, qB=15-qA share each staged tile). 4 waves/block,
// grid (128, 8): XCD = bh%8 -> all 8 q-blocks of one (b,h) share one XCD L2
// (v6-proven: FETCH 166->75 MB).
// v8 deltas vs v6:
//  1. sV stride 72 -> 68 els (34 dw == 2 mod 32 -> 16 bank groups, <=2-way).
//     v7-proven: SQ_LDS_BANK_CONFLICT 7.09M -> 3.34M.
//  2. psum butterfly (16 ds_swizzle + 32 VALU per process) -> MFMA row-sum
//     o7 += P @ ones (MFMA pipe at 9%: free). v7-proven correct.
//  3. T5 s_setprio(1) around the MFMA clusters (m191: +4-7% on attn with
//     independent blocks per CU at different phases -- our regime).
// Fixed-reference softmax: p = exp(min(s,30)); final /rowsum. Causal mask on
// diagonal tile only (block-uniform).
// LDS: sK 13312 + sV 13056 + sP 9728 = 36096 B -> 4 blocks/CU.
// Do NOT add register state beyond ~112 VGPR (v4/v5: spills past 128).
// ---------------------------------------------------------------------------
__global__ __launch_bounds__(256) void attn_kernel(const bf16* __restrict__ qkv,
                                                   bf16* __restrict__ aout)
{
    constexpr int T = 1024, C3 = 2304, HD = 96, CC = 768;
    __shared__ bf16 sK[64 * 104];
    __shared__ bf16 sV[96 * 68];      // V transposed [d][key], stride 68
    __shared__ bf16 sP[4][16 * 76];
    const int tid = threadIdx.x;
    const int wave = tid >> 6, lane = tid & 63;
    const int quad = lane >> 4, l16 = lane & 15;
    const int bh = blockIdx.x, b = bh >> 3, h = bh & 7;
    const float scale = 0.10206207261596575f;  // 1/sqrt(96)

    const int qAi = blockIdx.y;       // 0..7
    const int qBi = 15 - qAi;         // 8..15
    const int q0A = qAi * 64 + wave * 16;
    const int q0B = qBi * 64 + wave * 16;

    const bf16* kgbase = qkv + (size_t)b * T * C3 + CC + h * HD;      // K
    const bf16* vgbase = qkv + (size_t)b * T * C3 + 2 * CC + h * HD;  // V
    bf16* sPw = &sP[wave][0];

    // staging index precompute (j = c*256 + tid)
    int kKey[3], kCh[3], vKey2[3], vDq[3];
#pragma unroll
    for (int c = 0; c < 3; ++c) {
        const int j = c * 256 + tid;
        kKey[c] = j / 12; kCh[c] = j - kKey[c] * 12;
        vKey2[c] = (j & 31) * 2; vDq[c] = j >> 5;
    }

    // Q A-frags for both tiles: A[m=l16][k=d], d = c*32 + quad*8 + j
    const bf16* qrA = qkv + (size_t)(b * T + q0A + l16) * C3 + h * HD + quad * 8;
    const bf16* qrB = qkv + (size_t)(b * T + q0B + l16) * C3 + h * HD + quad * 8;
    const bf16x8 aQA0 = *(const bf16x8*)(qrA);
    const bf16x8 aQA1 = *(const bf16x8*)(qrA + 32);
    const bf16x8 aQA2 = *(const bf16x8*)(qrA + 64);
    const bf16x8 aQB0 = *(const bf16x8*)(qrB);
    const bf16x8 aQB1 = *(const bf16x8*)(qrB + 32);
    const bf16x8 aQB2 = *(const bf16x8*)(qrB + 64);

    bf16x8 ones;
#pragma unroll
    for (int j = 0; j < 8; ++j) ones[j] = (bf16)1.0f;

    const f32x4 z4 = {0.f, 0.f, 0.f, 0.f};
    f32x4 oA[6], oB[6];
#pragma unroll
    for (int i = 0; i < 6; ++i) { oA[i] = z4; oB[i] = z4; }
    f32x4 o7A = z4, o7B = z4;   // row-sum accumulators (all cols identical)

    // one q-tile update against the staged sK/sV tile
    auto process = [&](const bf16x8& Q0, const bf16x8& Q1, const bf16x8& Q2,
                       f32x4 (&o)[6], f32x4& o7,
                       const int q0, const int kk0, const bool diag) {
        f32x4 s[4];
#pragma unroll
        for (int i = 0; i < 4; ++i) s[i] = z4;
        __builtin_amdgcn_s_setprio(1);
#pragma unroll
        for (int nt = 0; nt < 4; ++nt) {
            const bf16* kp = sK + (nt * 16 + l16) * 104 + quad * 8;
            const bf16x8 b0 = *(const bf16x8*)(kp);
            const bf16x8 b1 = *(const bf16x8*)(kp + 32);
            const bf16x8 b2 = *(const bf16x8*)(kp + 64);
            s[nt] = __builtin_amdgcn_mfma_f32_16x16x32_bf16(Q0, b0, s[nt], 0, 0, 0);
            s[nt] = __builtin_amdgcn_mfma_f32_16x16x32_bf16(Q1, b1, s[nt], 0, 0, 0);
            s[nt] = __builtin_amdgcn_mfma_f32_16x16x32_bf16(Q2, b2, s[nt], 0, 0, 0);
        }
        __builtin_amdgcn_s_setprio(0);

        // mask (diagonal tile only; block-uniform) + exp
#pragma unroll
        for (int nt = 0; nt < 4; ++nt)
#pragma unroll
            for (int reg = 0; reg < 4; ++reg) {
                float v = s[nt][reg] * scale;
                if (diag) {
                    const int qr = q0 + quad * 4 + reg;
                    const int key = kk0 + nt * 16 + l16;
                    v = (key > qr) ? -1e30f : v;
                }
                s[nt][reg] = __expf(fminf(v, 30.f));
            }

        // P: C-layout -> LDS (stride 76) -> A-layout, per-wave region
#pragma unroll
        for (int nt = 0; nt < 4; ++nt)
#pragma unroll
            for (int reg = 0; reg < 4; ++reg)
                sPw[(quad * 4 + reg) * 76 + nt * 16 + l16] = (bf16)s[nt][reg];
        __asm__ volatile("s_waitcnt lgkmcnt(0)" ::: "memory");

        const bf16x8 aP0 = *(const bf16x8*)(sPw + l16 * 76 + quad * 8);
        const bf16x8 aP1 = *(const bf16x8*)(sPw + l16 * 76 + 32 + quad * 8);
        __builtin_amdgcn_s_setprio(1);
        // row-sum via MFMA (B = ones): D[m][*] = sum_k P[m][k]
        o7 = __builtin_amdgcn_mfma_f32_16x16x32_bf16(aP0, ones, o7, 0, 0, 0);
        o7 = __builtin_amdgcn_mfma_f32_16x16x32_bf16(aP1, ones, o7, 0, 0, 0);
#pragma unroll
        for (int dd = 0; dd < 6; ++dd) {
            const bf16* vp = sV + (dd * 16 + l16) * 68 + quad * 8;
            const bf16x8 v0 = *(const bf16x8*)(vp);
            const bf16x8 v1 = *(const bf16x8*)(vp + 32);
            o[dd] = __builtin_amdgcn_mfma_f32_16x16x32_bf16(aP0, v0, o[dd], 0, 0, 0);
            o[dd] = __builtin_amdgcn_mfma_f32_16x16x32_bf16(aP1, v1, o[dd], 0, 0, 0);
        }
        __builtin_amdgcn_s_setprio(0);
    };

    for (int kb = 0; kb <= qBi; ++kb) {
        const int kk0 = kb * 64;

        __syncthreads();  // prior tile's sK/sV reads done
        // ---- stage K tile: sK[key][d] (rows padded to 104) ----
#pragma unroll
        for (int c = 0; c < 3; ++c) {
            const bf16x8 kv = *(const bf16x8*)(kgbase +
                                (size_t)(kk0 + kKey[c]) * C3 + kCh[c] * 8);
            *(bf16x8*)(sK + kKey[c] * 104 + kCh[c] * 8) = kv;
        }
        // ---- stage V tile: sV[d][key] (packed b32, stride 68) ----
#pragma unroll
        for (int c = 0; c < 3; ++c) {
            const bf16* p0 = vgbase + (size_t)(kk0 + vKey2[c]) * C3 + vDq[c] * 4;
            const bf16x4 va = *(const bf16x4*)p0;
            const bf16x4 vb = *(const bf16x4*)(p0 + C3);
#pragma unroll
            for (int jj = 0; jj < 4; ++jj) {
                bf16x2 pk; pk[0] = va[jj]; pk[1] = vb[jj];
                *(bf16x2*)(sV + (vDq[c] * 4 + jj) * 68 + vKey2[c]) = pk;
            }
        }
        __syncthreads();

        // qB every tile; qA while kb <= qAi (both block-uniform)
        process(aQB0, aQB1, aQB2, oB, o7B, q0B, kk0, kb == qBi);
        if (kb <= qAi)
            process(aQA0, aQA1, aQA2, oA, o7A, q0A, kk0, kb == qAi);
    }

    // ---- write both outputs: aout[b, t, h*96 + d] ----
    bf16* opA = aout + (size_t)(b * T + q0A + quad * 4) * CC + h * HD + l16;
    bf16* opB = aout + (size_t)(b * T + q0B + quad * 4) * CC + h * HD + l16;
#pragma unroll
    for (int reg = 0; reg < 4; ++reg) {
        const float invA = 1.f / o7A[reg];
        const float invB = 1.f / o7B[reg];
#pragma unroll
        for (int dd = 0; dd < 6; ++dd) {
            opA[(size_t)reg * CC + dd * 16] = (bf16)(oA[dd][reg] * invA);
            opB[(size_t)reg * CC + dd * 16] = (bf16)(oB[dd][reg] * invB);
        }
    }
}

// ===========================================================================
extern "C" void kernel_launch(void* const* d_in, const int* in_sizes, int n_in,
                              void* d_out, int out_size, void* d_ws, size_t ws_size,
                              hipStream_t stream)
{
    const float* x      = (const float*)d_in[0];
    const float* ln1_g  = (const float*)d_in[1];
    const float* ln1_b  = (const float*)d_in[2];
    const float* attn_w = (const float*)d_in[3];
    const float* attn_b = (const float*)d_in[4];
    const float* proj_w = (const float*)d_in[5];
    const float* proj_b = (const float*)d_in[6];
    const float* ln2_g  = (const float*)d_in[7];
    const float* ln2_b  = (const float*)d_in[8];
    const float* fc_w   = (const float*)d_in[9];
    const float* fc_b   = (const float*)d_in[10];
    const float* fc2_w  = (const float*)d_in[11];
    const float* fc2_b  = (const float*)d_in[12];

    char* ws = (char*)d_ws;
    bf16*  attn_wT = (bf16*)(ws + 0);
    bf16*  proj_wT = (bf16*)(ws + 3538944);
    bf16*  fc_wT   = (bf16*)(ws + 4718592);
    bf16*  fc2_wT  = (bf16*)(ws + 9437184);
    bf16*  hbuf    = (bf16*)(ws + 14155776);   // h -> attn_out -> h2
    bf16*  qkv     = (bf16*)(ws + 39321600);   // dead after attention
    bf16*  x1      = (bf16*)(ws + 39321600);   // aliases dead qkv
    bf16*  act     = (bf16*)(ws + 64487424);   // [8192][3072] chunk buffer

    const dim3 tb(32, 8);

    wtrans<<<dim3(72, 24), tb, 0, stream>>>(attn_w, attn_wT, 768, 2304);
    wtrans<<<dim3(24, 24), tb, 0, stream>>>(proj_w, proj_wT, 768, 768);
    wtrans<<<dim3(96, 24), tb, 0, stream>>>(fc_w, fc_wT, 768, 3072);
    wtrans<<<dim3(24, 96), tb, 0, stream>>>(fc2_w, fc2_wT, 3072, 768);

    // LN1: x (f32) -> h (bf16)
    ln_kernel<float><<<4096, 256, 0, stream>>>(x, ln1_g, ln1_b, hbuf);

    // QKV GEMM
    gemm_bt<0, 128><<<dim3(18, 128), 256, 0, stream>>>(
        hbuf, attn_wT, attn_b, nullptr, qkv, 16384, 2304, 768);

    // attention -> hbuf (attn_out); merged-pair causal, grid (bh, qA):
    // XCD = bh%8 so all q-blocks of one (b,h) share one XCD's L2.
    attn_kernel<<<dim3(128, 8), 256, 0, stream>>>(qkv, hbuf);

    // proj + residual: x1 (bf16, aliases dead qkv) = attn_out @ proj_w + b + x
    gemm_bt<1, 128><<<dim3(6, 128), 256, 0, stream>>>(
        hbuf, proj_wT, proj_b, x, x1, 16384, 768, 768);

    // LN2: x1 (bf16) -> h2 (bf16, in hbuf)
    ln_kernel<bf16><<<4096, 256, 0, stream>>>(x1, ln2_g, ln2_b, hbuf);

    // MLP in 2 chunks of 8192 rows; fc2 uses TN=64 (768 blocks = 3/CU)
    for (int c = 0; c < 2; ++c) {
        const size_t ro = (size_t)c * 8192;
        gemm_bt<2, 128><<<dim3(24, 64), 256, 0, stream>>>(
            hbuf + ro * 768, fc_wT, fc_b, nullptr, act, 8192, 3072, 768);
        gemm_bt<3, 64><<<dim3(12, 64), 256, 0, stream>>>(
            act, fc2_wT, fc2_b, x1 + ro * 768,
            (float*)d_out + ro * 768, 8192, 768, 3072);
    }
}

// Round 6
// 661.569 us; speedup vs baseline: 1.0976x; 1.0840x over previous
//
#include <hip/hip_runtime.h>

// ============================================================================
// GPT block: LN1 -> QKV GEMM -> causal attention -> proj(+res) -> LN2 ->
//            FC+GELU -> FC2(+res).  FP32 I/O; bf16 MFMA internals, fp32 accum.
// B=16 T=1024 C=768 H=8 D=96.
//
// Workspace layout (bytes), total 114,819,072 (proven):
//   [0         , 3,538,944 )  attn_wT [2304][768] bf16
//   [3,538,944 , 4,718,592 )  proj_wT [768][768]  bf16
//   [4,718,592 , 9,437,184 )  fc_wT   [3072][768] bf16
//   [9,437,184 , 14,155,776)  fc2_wT  [768][3072] bf16
//   [14,155,776, 39,321,600)  hbuf    [16384][768] bf16 (h / attn_out / h2)
//   [39,321,600, 114,819,072) qkv     [16384][2304] bf16  (live until attn)
//   [39,321,600, 64,487,424 ) x1      [16384][768] bf16   (alias, after attn)
//   [64,487,424, 114,819,072) act     [8192][3072] bf16   (MLP M/2 chunks)
// ============================================================================

typedef __bf16 bf16;
typedef __bf16 bf16x8 __attribute__((ext_vector_type(8)));
typedef __bf16 bf16x4 __attribute__((ext_vector_type(4)));
typedef __bf16 bf16x2 __attribute__((ext_vector_type(2)));
typedef float f32x4 __attribute__((ext_vector_type(4)));

__device__ __forceinline__ void async_copy16(const void* g, void* l)
{
    __builtin_amdgcn_global_load_lds((__attribute__((address_space(1))) void*)g,
                                     (__attribute__((address_space(3))) void*)l,
                                     16, 0, 0);
}

// Raw workgroup barrier WITHOUT the __syncthreads() vmcnt(0) drain.
// Callers must have issued s_waitcnt lgkmcnt(0) after their LDS writes.
__device__ __forceinline__ void bar_nodrain()
{
    __builtin_amdgcn_sched_barrier(0);
    __asm__ volatile("" ::: "memory");
    __builtin_amdgcn_s_barrier();
    __asm__ volatile("" ::: "memory");
    __builtin_amdgcn_sched_barrier(0);
}

// ---------------------------------------------------------------------------
// 32x32-tiled transpose + fp32->bf16: in[R][C] f32 -> out[C][R] bf16.
// ---------------------------------------------------------------------------
__global__ __launch_bounds__(256) void wtrans(const float* __restrict__ in,
                                              bf16* __restrict__ out,
                                              const int R, const int C)
{
    __shared__ float tile[32][33];
    const int c0 = blockIdx.x * 32, r0 = blockIdx.y * 32;
    const int tx = threadIdx.x, ty = threadIdx.y;
#pragma unroll
    for (int i = 0; i < 4; ++i)
        tile[ty + i * 8][tx] = in[(size_t)(r0 + ty + i * 8) * C + c0 + tx];
    __syncthreads();
#pragma unroll
    for (int i = 0; i < 4; ++i)
        out[(size_t)(c0 + ty + i * 8) * R + r0 + tx] = (bf16)tile[tx][ty + i * 8];
}

// ---------------------------------------------------------------------------
// LayerNorm over C=768. One wave per row, 4 rows/block. TIN = float or bf16.
// ---------------------------------------------------------------------------
template <typename TIN>
__global__ __launch_bounds__(256) void ln_kernel(const TIN* __restrict__ x,
                                                 const float* __restrict__ g,
                                                 const float* __restrict__ bb,
                                                 bf16* __restrict__ out)
{
    const int wave = threadIdx.x >> 6, lane = threadIdx.x & 63;
    const size_t row = (size_t)blockIdx.x * 4 + wave;
    const TIN* xr = x + row * 768;
    float v[12];
    float s = 0.f;
#pragma unroll
    for (int c = 0; c < 3; ++c) {
        if constexpr (sizeof(TIN) == 2) {
            const bf16x4 t4 = *(const bf16x4*)(xr + c * 256 + lane * 4);
#pragma unroll
            for (int j = 0; j < 4; ++j) { v[c * 4 + j] = (float)t4[j]; s += v[c * 4 + j]; }
        } else {
            const float4 t4 = *(const float4*)(xr + c * 256 + lane * 4);
            v[c * 4 + 0] = t4.x; v[c * 4 + 1] = t4.y;
            v[c * 4 + 2] = t4.z; v[c * 4 + 3] = t4.w;
            s += t4.x + t4.y + t4.z + t4.w;
        }
    }
#pragma unroll
    for (int off = 32; off >= 1; off >>= 1) s += __shfl_xor(s, off, 64);
    const float mu = s * (1.f / 768.f);
    float q = 0.f;
#pragma unroll
    for (int i = 0; i < 12; ++i) { const float d = v[i] - mu; q += d * d; }
#pragma unroll
    for (int off = 32; off >= 1; off >>= 1) q += __shfl_xor(q, off, 64);
    const float rs = rsqrtf(q * (1.f / 768.f) + 1e-5f);
#pragma unroll
    for (int c = 0; c < 3; ++c) {
        const float4 gv = *(const float4*)(g + c * 256 + lane * 4);
        const float4 bv = *(const float4*)(bb + c * 256 + lane * 4);
        bf16x4 ov;
        ov[0] = (bf16)((v[c * 4 + 0] - mu) * rs * gv.x + bv.x);
        ov[1] = (bf16)((v[c * 4 + 1] - mu) * rs * gv.y + bv.y);
        ov[2] = (bf16)((v[c * 4 + 2] - mu) * rs * gv.z + bv.z);
        ov[3] = (bf16)((v[c * 4 + 3] - mu) * rs * gv.w + bv.w);
        *(bf16x4*)(out + row * 768 + c * 256 + lane * 4) = ov;
    }
}

// ---------------------------------------------------------------------------
// bf16 GEMM: C[M,N] = A[M,K] * Bt[N,K]^T (+ epilogue). BK=64 as two stacked
// BK=32 LDS images; global_load_lds staging; 128xTN tile, 4 waves. K%64==0.
// EPI: 0 bias->bf16 | 1 bias+res(f32)->bf16 | 2 bias+GELU->bf16
//      3 bias+res(bf16)->f32
// ---------------------------------------------------------------------------
template <int EPI, int TN>
__global__ __launch_bounds__(256) void gemm_bt(const bf16* __restrict__ A,
                                               const bf16* __restrict__ Bt,
                                               const float* __restrict__ bias,
                                               const void* __restrict__ res,
                                               void* __restrict__ out,
                                               const int M, const int N, const int K)
{
    constexpr int NT_W = TN / 32;           // nt tiles per wave
    constexpr int NCPB = (TN * 8) / 256;    // B staging copies (4 or 2)
    __shared__ bf16 sA[2 * 128 * 32];       // image ks at sA + ks*4096
    __shared__ bf16 sB[2 * TN * 32];        // image ks at sB + ks*TN*32
    const int t = threadIdx.x;
    const int wave = t >> 6, lane = t & 63;
    const int quad = lane >> 4, l16 = lane & 15;
    const int bm0 = blockIdx.y * 128, bn0 = blockIdx.x * TN;
    const int wm = (wave >> 1) * 64, wn = (wave & 1) * (TN / 2);

    const f32x4 z4 = {0.f, 0.f, 0.f, 0.f};
    f32x4 acc[4][NT_W];
#pragma unroll
    for (int i = 0; i < 4; ++i)
#pragma unroll
        for (int j = 0; j < NT_W; ++j) acc[i][j] = z4;

    const bf16* gAp[4]; bf16* lAp[4];
#pragma unroll
    for (int c = 0; c < 4; ++c) {
        const int j = c * 256 + t;
        const int img = j >> 9, r = (j >> 2) & 127, k8 = j & 3;
        gAp[c] = A + (size_t)(bm0 + r) * K + img * 32 + k8 * 8;
        lAp[c] = sA + j * 8;
    }
    const bf16* gBp[NCPB]; bf16* lBp[NCPB];
#pragma unroll
    for (int c = 0; c < NCPB; ++c) {
        const int j = c * 256 + t;
        const int img = j / (TN * 4), r = (j % (TN * 4)) >> 2, k8 = j & 3;
        gBp[c] = Bt + (size_t)(bn0 + r) * K + img * 32 + k8 * 8;
        lBp[c] = sB + j * 8;
    }

    for (int kt = 0; kt < K; kt += 64) {
        __syncthreads();
#pragma unroll
        for (int c = 0; c < 4; ++c) async_copy16(gAp[c] + kt, lAp[c]);
#pragma unroll
        for (int c = 0; c < NCPB; ++c) async_copy16(gBp[c] + kt, lBp[c]);
        __syncthreads();

#pragma unroll
        for (int ks = 0; ks < 2; ++ks) {
            bf16x8 af[4], bfm[NT_W];
#pragma unroll
            for (int mt = 0; mt < 4; ++mt)
                af[mt] = *(const bf16x8*)(sA + ks * 4096 +
                                          (wm + mt * 16 + l16) * 32 + quad * 8);
#pragma unroll
            for (int nt = 0; nt < NT_W; ++nt)
                bfm[nt] = *(const bf16x8*)(sB + ks * (TN * 32) +
                                           (wn + nt * 16 + l16) * 32 + quad * 8);
#pragma unroll
            for (int mt = 0; mt < 4; ++mt)
#pragma unroll
                for (int nt = 0; nt < NT_W; ++nt)
                    acc[mt][nt] = __builtin_amdgcn_mfma_f32_16x16x32_bf16(
                        af[mt], bfm[nt], acc[mt][nt], 0, 0, 0);
        }
    }

    // C/D layout: row = quad*4 + reg, col = l16 (per 16x16 tile).
    const int rb = bm0 + wm + quad * 4;
    const int cb = bn0 + wn + l16;
#pragma unroll
    for (int mt = 0; mt < 4; ++mt) {
#pragma unroll
        for (int nt = 0; nt < NT_W; ++nt) {
            const int col = cb + nt * 16;
            const float bv = bias[col];
#pragma unroll
            for (int reg = 0; reg < 4; ++reg) {
                const size_t idx = (size_t)(rb + mt * 16 + reg) * N + col;
                float v = acc[mt][nt][reg] + bv;
                if constexpr (EPI == 1) {
                    ((bf16*)out)[idx] = (bf16)(v + ((const float*)res)[idx]);
                } else if constexpr (EPI == 2) {
                    const float u = v;
                    const float a2 = 1.5957691216057308f *
                                     (u + 0.044715f * u * u * u);
                    v = u / (1.f + __expf(-a2));
                    ((bf16*)out)[idx] = (bf16)v;
                } else if constexpr (EPI == 3) {
                    ((float*)out)[idx] = v + (float)((const bf16*)res)[idx];
                } else {
                    ((bf16*)out)[idx] = (bf16)v;
                }
            }
        }
    }
}

// ---------------------------------------------------------------------------
// Causal flash attention v9 = v6 proven body (stride-72 sV, butterfly psum,
// NO setprio / NO row-sum / NO stride-68: v7/v8's +50us regression lives in
// that change set and is unattributed -- all suspects reverted) + v5's
// register-prefetch pipeline with no-drain barriers, this time WITHOUT the
// launch_bounds cap that spilled v5 (VGPR cap 64 -> 415MB scratch traffic).
//
// Pipeline protocol (correctness-proven by v5's passing run):
//   issue_tile(0)                       (9 global loads -> regs, in flight)
//   loop: bar_nodrain                   (prior tile's LDS reads done)
//         write regs -> sK/sV           (compiler vmcnt-waits tile k's loads;
//                                        they landed during last compute)
//         issue_tile(k+1)               (loads ride across the barrier)
//         lgkmcnt(0); bar_nodrain       (ds_writes visible; NO vmcnt drain)
//         process(qB); process(qA)      (~500cy compute hides next loads)
// Merged pair (qA, qB=15-qA share each staged tile). 4 waves/block,
// grid (128, 8): XCD = bh%8 (v6-proven: FETCH 166->75 MB).
// Causal mask diagonal tile only. Fixed-ref softmax: p=exp(min(s,30)), /sum.
// LDS: sK 13312 + sV 13824 + sP 9728 = 36864 B -> 4 blocks/CU by LDS.
// VGPR ~104+24 prefetch ~= 128. KILL-CRITERIA: if WRITE_SIZE >> 25MB again
// (spills), revert attn to v6 permanently.
// ---------------------------------------------------------------------------
__global__ __launch_bounds__(256) void attn_kernel(const bf16* __restrict__ qkv,
                                                   bf16* __restrict__ aout)
{
    constexpr int T = 1024, C3 = 2304, HD = 96, CC = 768;
    __shared__ bf16 sK[64 * 104];
    __shared__ bf16 sV[96 * 72];
    __shared__ bf16 sP[4][16 * 76];
    const int tid = threadIdx.x;
    const int wave = tid >> 6, lane = tid & 63;
    const int quad = lane >> 4, l16 = lane & 15;
    const int bh = blockIdx.x, b = bh >> 3, h = bh & 7;
    const float scale = 0.10206207261596575f;  // 1/sqrt(96)

    const int qAi = blockIdx.y;       // 0..7
    const int qBi = 15 - qAi;         // 8..15
    const int q0A = qAi * 64 + wave * 16;
    const int q0B = qBi * 64 + wave * 16;

    const bf16* kgbase = qkv + (size_t)b * T * C3 + CC + h * HD;      // K
    const bf16* vgbase = qkv + (size_t)b * T * C3 + 2 * CC + h * HD;  // V
    bf16* sPw = &sP[wave][0];

    // staging index precompute (j = c*256 + tid)
    int kKey[3], kCh[3], vKey2[3], vDq[3];
#pragma unroll
    for (int c = 0; c < 3; ++c) {
        const int j = c * 256 + tid;
        kKey[c] = j / 12; kCh[c] = j - kKey[c] * 12;
        vKey2[c] = (j & 31) * 2; vDq[c] = j >> 5;
    }

    // Q A-frags for both tiles: A[m=l16][k=d], d = c*32 + quad*8 + j
    const bf16* qrA = qkv + (size_t)(b * T + q0A + l16) * C3 + h * HD + quad * 8;
    const bf16* qrB = qkv + (size_t)(b * T + q0B + l16) * C3 + h * HD + quad * 8;
    const bf16x8 aQA0 = *(const bf16x8*)(qrA);
    const bf16x8 aQA1 = *(const bf16x8*)(qrA + 32);
    const bf16x8 aQA2 = *(const bf16x8*)(qrA + 64);
    const bf16x8 aQB0 = *(const bf16x8*)(qrB);
    const bf16x8 aQB1 = *(const bf16x8*)(qrB + 32);
    const bf16x8 aQB2 = *(const bf16x8*)(qrB + 64);

    const f32x4 z4 = {0.f, 0.f, 0.f, 0.f};
    f32x4 oA[6], oB[6];
#pragma unroll
    for (int i = 0; i < 6; ++i) { oA[i] = z4; oB[i] = z4; }
    float lA[4] = {0.f, 0.f, 0.f, 0.f}, lB[4] = {0.f, 0.f, 0.f, 0.f};

    // prefetch registers: next tile's K (3x16B) and V (6x8B)
    bf16x8 kreg[3];
    bf16x4 va[3], vb[3];
    auto issue_tile = [&](const int kk0) {
#pragma unroll
        for (int c = 0; c < 3; ++c) {
            kreg[c] = *(const bf16x8*)(kgbase + (size_t)(kk0 + kKey[c]) * C3 +
                                       kCh[c] * 8);
            const bf16* p0 = vgbase + (size_t)(kk0 + vKey2[c]) * C3 + vDq[c] * 4;
            va[c] = *(const bf16x4*)p0;
            vb[c] = *(const bf16x4*)(p0 + C3);
        }
    };

    // one q-tile update against the staged sK/sV tile (v6 body, unmodified)
    auto process = [&](const bf16x8& Q0, const bf16x8& Q1, const bf16x8& Q2,
                       f32x4 (&o)[6], float (&lrow)[4],
                       const int q0, const int kk0, const bool diag) {
        f32x4 s[4];
#pragma unroll
        for (int i = 0; i < 4; ++i) s[i] = z4;
#pragma unroll
        for (int nt = 0; nt < 4; ++nt) {
            const bf16* kp = sK + (nt * 16 + l16) * 104 + quad * 8;
            const bf16x8 b0 = *(const bf16x8*)(kp);
            const bf16x8 b1 = *(const bf16x8*)(kp + 32);
            const bf16x8 b2 = *(const bf16x8*)(kp + 64);
            s[nt] = __builtin_amdgcn_mfma_f32_16x16x32_bf16(Q0, b0, s[nt], 0, 0, 0);
            s[nt] = __builtin_amdgcn_mfma_f32_16x16x32_bf16(Q1, b1, s[nt], 0, 0, 0);
            s[nt] = __builtin_amdgcn_mfma_f32_16x16x32_bf16(Q2, b2, s[nt], 0, 0, 0);
        }

        // mask (diagonal tile only; block-uniform) + exp
        float psum[4] = {0.f, 0.f, 0.f, 0.f};
#pragma unroll
        for (int nt = 0; nt < 4; ++nt)
#pragma unroll
            for (int reg = 0; reg < 4; ++reg) {
                float v = s[nt][reg] * scale;
                if (diag) {
                    const int qr = q0 + quad * 4 + reg;
                    const int key = kk0 + nt * 16 + l16;
                    v = (key > qr) ? -1e30f : v;
                }
                const float p = __expf(fminf(v, 30.f));
                s[nt][reg] = p;
                psum[reg] += p;
            }

        // P: C-layout -> LDS (stride 76) -> A-layout, per-wave region
#pragma unroll
        for (int nt = 0; nt < 4; ++nt)
#pragma unroll
            for (int reg = 0; reg < 4; ++reg)
                sPw[(quad * 4 + reg) * 76 + nt * 16 + l16] = (bf16)s[nt][reg];
        __asm__ volatile("s_waitcnt lgkmcnt(0)" ::: "memory");

        // psum butterfly over the 16-lane row group (independent of PV)
#pragma unroll
        for (int off = 1; off < 16; off <<= 1)
#pragma unroll
            for (int reg = 0; reg < 4; ++reg)
                psum[reg] += __shfl_xor(psum[reg], off, 64);
#pragma unroll
        for (int reg = 0; reg < 4; ++reg) lrow[reg] += psum[reg];

        const bf16x8 aP0 = *(const bf16x8*)(sPw + l16 * 76 + quad * 8);
        const bf16x8 aP1 = *(const bf16x8*)(sPw + l16 * 76 + 32 + quad * 8);
#pragma unroll
        for (int dd = 0; dd < 6; ++dd) {
            const bf16* vp = sV + (dd * 16 + l16) * 72 + quad * 8;
            const bf16x8 v0 = *(const bf16x8*)(vp);
            const bf16x8 v1 = *(const bf16x8*)(vp + 32);
            o[dd] = __builtin_amdgcn_mfma_f32_16x16x32_bf16(aP0, v0, o[dd], 0, 0, 0);
            o[dd] = __builtin_amdgcn_mfma_f32_16x16x32_bf16(aP1, v1, o[dd], 0, 0, 0);
        }
    };

    issue_tile(0);  // tile-0 loads in flight (only exposed wait of the block)

    for (int kb = 0; kb <= qBi; ++kb) {
        const int kk0 = kb * 64;

        bar_nodrain();  // prior tile's sK/sV reads done (no vmcnt drain!)

        // ---- write prefetched K tile: sK[key][d] (rows padded to 104) ----
#pragma unroll
        for (int c = 0; c < 3; ++c)
            *(bf16x8*)(sK + kKey[c] * 104 + kCh[c] * 8) = kreg[c];
        // ---- write prefetched V tile: sV[d][key] (packed b32) ----
#pragma unroll
        for (int c = 0; c < 3; ++c) {
#pragma unroll
            for (int jj = 0; jj < 4; ++jj) {
                bf16x2 pk; pk[0] = va[c][jj]; pk[1] = vb[c][jj];
                *(bf16x2*)(sV + (vDq[c] * 4 + jj) * 72 + vKey2[c]) = pk;
            }
        }

        // issue next tile's global loads AFTER the LDS writes consumed the
        // old register values; they ride across the barrier (vmcnt never
        // drained) and land during the compute phase below.
        if (kb < qBi) issue_tile(kk0 + 64);

        __asm__ volatile("s_waitcnt lgkmcnt(0)" ::: "memory");  // ds_writes visible
        bar_nodrain();

        // qB every tile; qA while kb <= qAi (both block-uniform)
        process(aQB0, aQB1, aQB2, oB, lB, q0B, kk0, kb == qBi);
        if (kb <= qAi)
            process(aQA0, aQA1, aQA2, oA, lA, q0A, kk0, kb == qAi);
    }

    // ---- write both outputs: aout[b, t, h*96 + d] ----
    bf16* opA = aout + (size_t)(b * T + q0A + quad * 4) * CC + h * HD + l16;
    bf16* opB = aout + (size_t)(b * T + q0B + quad * 4) * CC + h * HD + l16;
#pragma unroll
    for (int reg = 0; reg < 4; ++reg) {
        const float invA = 1.f / lA[reg];
        const float invB = 1.f / lB[reg];
#pragma unroll
        for (int dd = 0; dd < 6; ++dd) {
            opA[(size_t)reg * CC + dd * 16] = (bf16)(oA[dd][reg] * invA);
            opB[(size_t)reg * CC + dd * 16] = (bf16)(oB[dd][reg] * invB);
        }
    }
}

// ===========================================================================
extern "C" void kernel_launch(void* const* d_in, const int* in_sizes, int n_in,
                              void* d_out, int out_size, void* d_ws, size_t ws_size,
                              hipStream_t stream)
{
    const float* x      = (const float*)d_in[0];
    const float* ln1_g  = (const float*)d_in[1];
    const float* ln1_b  = (const float*)d_in[2];
    const float* attn_w = (const float*)d_in[3];
    const float* attn_b = (const float*)d_in[4];
    const float* proj_w = (const float*)d_in[5];
    const float* proj_b = (const float*)d_in[6];
    const float* ln2_g  = (const float*)d_in[7];
    const float* ln2_b  = (const float*)d_in[8];
    const float* fc_w   = (const float*)d_in[9];
    const float* fc_b   = (const float*)d_in[10];
    const float* fc2_w  = (const float*)d_in[11];
    const float* fc2_b  = (const float*)d_in[12];

    char* ws = (char*)d_ws;
    bf16*  attn_wT = (bf16*)(ws + 0);
    bf16*  proj_wT = (bf16*)(ws + 3538944);
    bf16*  fc_wT   = (bf16*)(ws + 4718592);
    bf16*  fc2_wT  = (bf16*)(ws + 9437184);
    bf16*  hbuf    = (bf16*)(ws + 14155776);   // h -> attn_out -> h2
    bf16*  qkv     = (bf16*)(ws + 39321600);   // dead after attention
    bf16*  x1      = (bf16*)(ws + 39321600);   // aliases dead qkv
    bf16*  act     = (bf16*)(ws + 64487424);   // [8192][3072] chunk buffer

    const dim3 tb(32, 8);

    wtrans<<<dim3(72, 24), tb, 0, stream>>>(attn_w, attn_wT, 768, 2304);
    wtrans<<<dim3(24, 24), tb, 0, stream>>>(proj_w, proj_wT, 768, 768);
    wtrans<<<dim3(96, 24), tb, 0, stream>>>(fc_w, fc_wT, 768, 3072);
    wtrans<<<dim3(24, 96), tb, 0, stream>>>(fc2_w, fc2_wT, 3072, 768);

    // LN1: x (f32) -> h (bf16)
    ln_kernel<float><<<4096, 256, 0, stream>>>(x, ln1_g, ln1_b, hbuf);

    // QKV GEMM
    gemm_bt<0, 128><<<dim3(18, 128), 256, 0, stream>>>(
        hbuf, attn_wT, attn_b, nullptr, qkv, 16384, 2304, 768);

    // attention -> hbuf (attn_out); merged-pair causal, grid (bh, qA):
    // XCD = bh%8 so all q-blocks of one (b,h) share one XCD's L2.
    attn_kernel<<<dim3(128, 8), 256, 0, stream>>>(qkv, hbuf);

    // proj + residual: x1 (bf16, aliases dead qkv) = attn_out @ proj_w + b + x
    gemm_bt<1, 128><<<dim3(6, 128), 256, 0, stream>>>(
        hbuf, proj_wT, proj_b, x, x1, 16384, 768, 768);

    // LN2: x1 (bf16) -> h2 (bf16, in hbuf)
    ln_kernel<bf16><<<4096, 256, 0, stream>>>(x1, ln2_g, ln2_b, hbuf);

    // MLP in 2 chunks of 8192 rows; fc2 uses TN=64 (768 blocks = 3/CU)
    for (int c = 0; c < 2; ++c) {
        const size_t ro = (size_t)c * 8192;
        gemm_bt<2, 128><<<dim3(24, 64), 256, 0, stream>>>(
            hbuf + ro * 768, fc_wT, fc_b, nullptr, act, 8192, 3072, 768);
        gemm_bt<3, 64><<<dim3(12, 64), 256, 0, stream>>>(
            act, fc2_wT, fc2_b, x1 + ro * 768,
            (float*)d_out + ro * 768, 8192, 768, 3072);
    }
}

// Round 7
// 595.255 us; speedup vs baseline: 1.2199x; 1.1114x over previous
//
#include <hip/hip_runtime.h>

// ============================================================================
// GPT block: LN1 -> QKV GEMM -> causal attention -> proj(+res) -> LN2 ->
//            FC+GELU -> FC2(+res).  FP32 I/O; bf16 MFMA internals, fp32 accum.
// B=16 T=1024 C=768 H=8 D=96.
//
// Workspace layout (bytes), total 114,819,072 (proven):
//   [0         , 3,538,944 )  attn_wT [2304][768] bf16
//   [3,538,944 , 4,718,592 )  proj_wT [768][768]  bf16
//   [4,718,592 , 9,437,184 )  fc_wT   [3072][768] bf16
//   [9,437,184 , 14,155,776)  fc2_wT  [768][3072] bf16
//   [14,155,776, 39,321,600)  hbuf    [16384][768] bf16 (h / attn_out / h2)
//   [39,321,600, 114,819,072) qkv     [16384][2304] bf16  (live until attn)
//   [39,321,600, 64,487,424 ) x1      [16384][768] bf16   (alias, after attn)
//   [64,487,424, 114,819,072) act     [8192][3072] bf16   (MLP M/2 chunks)
// ============================================================================

typedef __bf16 bf16;
typedef __bf16 bf16x8 __attribute__((ext_vector_type(8)));
typedef __bf16 bf16x4 __attribute__((ext_vector_type(4)));
typedef __bf16 bf16x2 __attribute__((ext_vector_type(2)));
typedef float f32x4 __attribute__((ext_vector_type(4)));

__device__ __forceinline__ void async_copy16(const void* g, void* l)
{
    __builtin_amdgcn_global_load_lds((__attribute__((address_space(1))) void*)g,
                                     (__attribute__((address_space(3))) void*)l,
                                     16, 0, 0);
}

// Raw workgroup barrier WITHOUT the __syncthreads() vmcnt(0) drain.
// Callers must have issued s_waitcnt lgkmcnt(0) after their LDS writes.
__device__ __forceinline__ void bar_nodrain()
{
    __builtin_amdgcn_sched_barrier(0);
    __asm__ volatile("" ::: "memory");
    __builtin_amdgcn_s_barrier();
    __asm__ volatile("" ::: "memory");
    __builtin_amdgcn_sched_barrier(0);
}

// ---------------------------------------------------------------------------
// Batched 32x32-tiled transpose + fp32->bf16 for all 4 weight matrices in a
// single launch (was 4 launches; saves 3 launch/serialization gaps).
// Block ranges (flattened): attn_w [0,1728) 72x24 | proj [1728,2304) 24x24 |
// fc [2304,4608) 96x24 | fc2 [4608,6912) 24x96.
// ---------------------------------------------------------------------------
__global__ __launch_bounds__(256) void wtrans4(const float* __restrict__ aw, bf16* __restrict__ awT,
                                               const float* __restrict__ pw, bf16* __restrict__ pwT,
                                               const float* __restrict__ fw, bf16* __restrict__ fwT,
                                               const float* __restrict__ f2w, bf16* __restrict__ f2wT)
{
    __shared__ float tile[32][33];
    int id = blockIdx.x;
    const float* in; bf16* out; int R, C, nx;
    if (id < 1728)      { in = aw;  out = awT;  R = 768;  C = 2304; nx = 72; }
    else if (id < 2304) { in = pw;  out = pwT;  R = 768;  C = 768;  nx = 24; id -= 1728; }
    else if (id < 4608) { in = fw;  out = fwT;  R = 768;  C = 3072; nx = 96; id -= 2304; }
    else                { in = f2w; out = f2wT; R = 3072; C = 768;  nx = 24; id -= 4608; }
    const int c0 = (id % nx) * 32, r0 = (id / nx) * 32;
    const int tx = threadIdx.x, ty = threadIdx.y;
#pragma unroll
    for (int i = 0; i < 4; ++i)
        tile[ty + i * 8][tx] = in[(size_t)(r0 + ty + i * 8) * C + c0 + tx];
    __syncthreads();
#pragma unroll
    for (int i = 0; i < 4; ++i)
        out[(size_t)(c0 + ty + i * 8) * R + r0 + tx] = (bf16)tile[tx][ty + i * 8];
}

// ---------------------------------------------------------------------------
// LayerNorm over C=768. One wave per row, 4 rows/block. TIN = float or bf16.
// ---------------------------------------------------------------------------
template <typename TIN>
__global__ __launch_bounds__(256) void ln_kernel(const TIN* __restrict__ x,
                                                 const float* __restrict__ g,
                                                 const float* __restrict__ bb,
                                                 bf16* __restrict__ out)
{
    const int wave = threadIdx.x >> 6, lane = threadIdx.x & 63;
    const size_t row = (size_t)blockIdx.x * 4 + wave;
    const TIN* xr = x + row * 768;
    float v[12];
    float s = 0.f;
#pragma unroll
    for (int c = 0; c < 3; ++c) {
        if constexpr (sizeof(TIN) == 2) {
            const bf16x4 t4 = *(const bf16x4*)(xr + c * 256 + lane * 4);
#pragma unroll
            for (int j = 0; j < 4; ++j) { v[c * 4 + j] = (float)t4[j]; s += v[c * 4 + j]; }
        } else {
            const float4 t4 = *(const float4*)(xr + c * 256 + lane * 4);
            v[c * 4 + 0] = t4.x; v[c * 4 + 1] = t4.y;
            v[c * 4 + 2] = t4.z; v[c * 4 + 3] = t4.w;
            s += t4.x + t4.y + t4.z + t4.w;
        }
    }
#pragma unroll
    for (int off = 32; off >= 1; off >>= 1) s += __shfl_xor(s, off, 64);
    const float mu = s * (1.f / 768.f);
    float q = 0.f;
#pragma unroll
    for (int i = 0; i < 12; ++i) { const float d = v[i] - mu; q += d * d; }
#pragma unroll
    for (int off = 32; off >= 1; off >>= 1) q += __shfl_xor(q, off, 64);
    const float rs = rsqrtf(q * (1.f / 768.f) + 1e-5f);
#pragma unroll
    for (int c = 0; c < 3; ++c) {
        const float4 gv = *(const float4*)(g + c * 256 + lane * 4);
        const float4 bv = *(const float4*)(bb + c * 256 + lane * 4);
        bf16x4 ov;
        ov[0] = (bf16)((v[c * 4 + 0] - mu) * rs * gv.x + bv.x);
        ov[1] = (bf16)((v[c * 4 + 1] - mu) * rs * gv.y + bv.y);
        ov[2] = (bf16)((v[c * 4 + 2] - mu) * rs * gv.z + bv.z);
        ov[3] = (bf16)((v[c * 4 + 3] - mu) * rs * gv.w + bv.w);
        *(bf16x4*)(out + row * 768 + c * 256 + lane * 4) = ov;
    }
}

// ---------------------------------------------------------------------------
// bf16 GEMM: C[M,N] = A[M,K] * Bt[N,K]^T (+ epilogue). BK=64 as two stacked
// BK=32 LDS images; global_load_lds staging; 128xTN tile, 4 waves. K%64==0.
// EPI: 0 bias->bf16 | 1 bias+res(f32)->bf16 | 2 bias+GELU->bf16
//      3 bias+res(bf16)->f32
// v10: XCD A-panel grouping -- grid is (M/128, N/TN) and bm0 comes from
// blockIdx.x. All M/128 values are %8==0, so XCD = linear%8 = bm_idx%8:
// every block sharing an A row-panel (incl. fc2's 50MB act operand) lands on
// ONE XCD -> panel fetched once into that L2, other readers hit. Weights
// (<=4.7MB) L2-resident per XCD regardless.
// ---------------------------------------------------------------------------
template <int EPI, int TN>
__global__ __launch_bounds__(256) void gemm_bt(const bf16* __restrict__ A,
                                               const bf16* __restrict__ Bt,
                                               const float* __restrict__ bias,
                                               const void* __restrict__ res,
                                               void* __restrict__ out,
                                               const int M, const int N, const int K)
{
    constexpr int NT_W = TN / 32;           // nt tiles per wave
    constexpr int NCPB = (TN * 8) / 256;    // B staging copies (4 or 2)
    __shared__ bf16 sA[2 * 128 * 32];       // image ks at sA + ks*4096
    __shared__ bf16 sB[2 * TN * 32];        // image ks at sB + ks*TN*32
    const int t = threadIdx.x;
    const int wave = t >> 6, lane = t & 63;
    const int quad = lane >> 4, l16 = lane & 15;
    const int bm0 = blockIdx.x * 128, bn0 = blockIdx.y * TN;   // v10 swap
    const int wm = (wave >> 1) * 64, wn = (wave & 1) * (TN / 2);

    const f32x4 z4 = {0.f, 0.f, 0.f, 0.f};
    f32x4 acc[4][NT_W];
#pragma unroll
    for (int i = 0; i < 4; ++i)
#pragma unroll
        for (int j = 0; j < NT_W; ++j) acc[i][j] = z4;

    const bf16* gAp[4]; bf16* lAp[4];
#pragma unroll
    for (int c = 0; c < 4; ++c) {
        const int j = c * 256 + t;
        const int img = j >> 9, r = (j >> 2) & 127, k8 = j & 3;
        gAp[c] = A + (size_t)(bm0 + r) * K + img * 32 + k8 * 8;
        lAp[c] = sA + j * 8;
    }
    const bf16* gBp[NCPB]; bf16* lBp[NCPB];
#pragma unroll
    for (int c = 0; c < NCPB; ++c) {
        const int j = c * 256 + t;
        const int img = j / (TN * 4), r = (j % (TN * 4)) >> 2, k8 = j & 3;
        gBp[c] = Bt + (size_t)(bn0 + r) * K + img * 32 + k8 * 8;
        lBp[c] = sB + j * 8;
    }

    for (int kt = 0; kt < K; kt += 64) {
        __syncthreads();
#pragma unroll
        for (int c = 0; c < 4; ++c) async_copy16(gAp[c] + kt, lAp[c]);
#pragma unroll
        for (int c = 0; c < NCPB; ++c) async_copy16(gBp[c] + kt, lBp[c]);
        __syncthreads();

#pragma unroll
        for (int ks = 0; ks < 2; ++ks) {
            bf16x8 af[4], bfm[NT_W];
#pragma unroll
            for (int mt = 0; mt < 4; ++mt)
                af[mt] = *(const bf16x8*)(sA + ks * 4096 +
                                          (wm + mt * 16 + l16) * 32 + quad * 8);
#pragma unroll
            for (int nt = 0; nt < NT_W; ++nt)
                bfm[nt] = *(const bf16x8*)(sB + ks * (TN * 32) +
                                           (wn + nt * 16 + l16) * 32 + quad * 8);
#pragma unroll
            for (int mt = 0; mt < 4; ++mt)
#pragma unroll
                for (int nt = 0; nt < NT_W; ++nt)
                    acc[mt][nt] = __builtin_amdgcn_mfma_f32_16x16x32_bf16(
                        af[mt], bfm[nt], acc[mt][nt], 0, 0, 0);
        }
    }

    // C/D layout: row = quad*4 + reg, col = l16 (per 16x16 tile).
    const int rb = bm0 + wm + quad * 4;
    const int cb = bn0 + wn + l16;
#pragma unroll
    for (int mt = 0; mt < 4; ++mt) {
#pragma unroll
        for (int nt = 0; nt < NT_W; ++nt) {
            const int col = cb + nt * 16;
            const float bv = bias[col];
#pragma unroll
            for (int reg = 0; reg < 4; ++reg) {
                const size_t idx = (size_t)(rb + mt * 16 + reg) * N + col;
                float v = acc[mt][nt][reg] + bv;
                if constexpr (EPI == 1) {
                    ((bf16*)out)[idx] = (bf16)(v + ((const float*)res)[idx]);
                } else if constexpr (EPI == 2) {
                    const float u = v;
                    const float a2 = 1.5957691216057308f *
                                     (u + 0.044715f * u * u * u);
                    v = u / (1.f + __expf(-a2));
                    ((bf16*)out)[idx] = (bf16)v;
                } else if constexpr (EPI == 3) {
                    ((float*)out)[idx] = v + (float)((const bf16*)res)[idx];
                } else {
                    ((bf16*)out)[idx] = (bf16)v;
                }
            }
        }
    }
}

// ---------------------------------------------------------------------------
// Causal flash attention v9 (FROZEN -- proven 97.2us, VGPR 116, no spill).
// v6 proven body (stride-72 sV, butterfly psum) + register-prefetch pipeline
// with no-drain barriers, default launch bounds.
// Pipeline protocol:
//   issue_tile(0)                       (9 global loads -> regs, in flight)
//   loop: bar_nodrain                   (prior tile's LDS reads done)
//         write regs -> sK/sV           (compiler vmcnt-waits tile k's loads)
//         issue_tile(k+1)               (loads ride across the barrier)
//         lgkmcnt(0); bar_nodrain       (ds_writes visible; NO vmcnt drain)
//         process(qB); process(qA)      (~500cy compute hides next loads)
// Merged pair (qA, qB=15-qA share each staged tile). 4 waves/block,
// grid (128, 8): XCD = bh%8 (FETCH 166->75 MB proven).
// Causal mask diagonal tile only. Fixed-ref softmax: p=exp(min(s,30)), /sum.
// LDS: sK 13312 + sV 13824 + sP 9728 = 36864 B -> 4 blocks/CU.
// ---------------------------------------------------------------------------
__global__ __launch_bounds__(256) void attn_kernel(const bf16* __restrict__ qkv,
                                                   bf16* __restrict__ aout)
{
    constexpr int T = 1024, C3 = 2304, HD = 96, CC = 768;
    __shared__ bf16 sK[64 * 104];
    __shared__ bf16 sV[96 * 72];
    __shared__ bf16 sP[4][16 * 76];
    const int tid = threadIdx.x;
    const int wave = tid >> 6, lane = tid & 63;
    const int quad = lane >> 4, l16 = lane & 15;
    const int bh = blockIdx.x, b = bh >> 3, h = bh & 7;
    const float scale = 0.10206207261596575f;  // 1/sqrt(96)

    const int qAi = blockIdx.y;       // 0..7
    const int qBi = 15 - qAi;         // 8..15
    const int q0A = qAi * 64 + wave * 16;
    const int q0B = qBi * 64 + wave * 16;

    const bf16* kgbase = qkv + (size_t)b * T * C3 + CC + h * HD;      // K
    const bf16* vgbase = qkv + (size_t)b * T * C3 + 2 * CC + h * HD;  // V
    bf16* sPw = &sP[wave][0];

    // staging index precompute (j = c*256 + tid)
    int kKey[3], kCh[3], vKey2[3], vDq[3];
#pragma unroll
    for (int c = 0; c < 3; ++c) {
        const int j = c * 256 + tid;
        kKey[c] = j / 12; kCh[c] = j - kKey[c] * 12;
        vKey2[c] = (j & 31) * 2; vDq[c] = j >> 5;
    }

    // Q A-frags for both tiles: A[m=l16][k=d], d = c*32 + quad*8 + j
    const bf16* qrA = qkv + (size_t)(b * T + q0A + l16) * C3 + h * HD + quad * 8;
    const bf16* qrB = qkv + (size_t)(b * T + q0B + l16) * C3 + h * HD + quad * 8;
    const bf16x8 aQA0 = *(const bf16x8*)(qrA);
    const bf16x8 aQA1 = *(const bf16x8*)(qrA + 32);
    const bf16x8 aQA2 = *(const bf16x8*)(qrA + 64);
    const bf16x8 aQB0 = *(const bf16x8*)(qrB);
    const bf16x8 aQB1 = *(const bf16x8*)(qrB + 32);
    const bf16x8 aQB2 = *(const bf16x8*)(qrB + 64);

    const f32x4 z4 = {0.f, 0.f, 0.f, 0.f};
    f32x4 oA[6], oB[6];
#pragma unroll
    for (int i = 0; i < 6; ++i) { oA[i] = z4; oB[i] = z4; }
    float lA[4] = {0.f, 0.f, 0.f, 0.f}, lB[4] = {0.f, 0.f, 0.f, 0.f};

    // prefetch registers: next tile's K (3x16B) and V (6x8B)
    bf16x8 kreg[3];
    bf16x4 va[3], vb[3];
    auto issue_tile = [&](const int kk0) {
#pragma unroll
        for (int c = 0; c < 3; ++c) {
            kreg[c] = *(const bf16x8*)(kgbase + (size_t)(kk0 + kKey[c]) * C3 +
                                       kCh[c] * 8);
            const bf16* p0 = vgbase + (size_t)(kk0 + vKey2[c]) * C3 + vDq[c] * 4;
            va[c] = *(const bf16x4*)p0;
            vb[c] = *(const bf16x4*)(p0 + C3);
        }
    };

    // one q-tile update against the staged sK/sV tile (v6 body, unmodified)
    auto process = [&](const bf16x8& Q0, const bf16x8& Q1, const bf16x8& Q2,
                       f32x4 (&o)[6], float (&lrow)[4],
                       const int q0, const int kk0, const bool diag) {
        f32x4 s[4];
#pragma unroll
        for (int i = 0; i < 4; ++i) s[i] = z4;
#pragma unroll
        for (int nt = 0; nt < 4; ++nt) {
            const bf16* kp = sK + (nt * 16 + l16) * 104 + quad * 8;
            const bf16x8 b0 = *(const bf16x8*)(kp);
            const bf16x8 b1 = *(const bf16x8*)(kp + 32);
            const bf16x8 b2 = *(const bf16x8*)(kp + 64);
            s[nt] = __builtin_amdgcn_mfma_f32_16x16x32_bf16(Q0, b0, s[nt], 0, 0, 0);
            s[nt] = __builtin_amdgcn_mfma_f32_16x16x32_bf16(Q1, b1, s[nt], 0, 0, 0);
            s[nt] = __builtin_amdgcn_mfma_f32_16x16x32_bf16(Q2, b2, s[nt], 0, 0, 0);
        }

        // mask (diagonal tile only; block-uniform) + exp
        float psum[4] = {0.f, 0.f, 0.f, 0.f};
#pragma unroll
        for (int nt = 0; nt < 4; ++nt)
#pragma unroll
            for (int reg = 0; reg < 4; ++reg) {
                float v = s[nt][reg] * scale;
                if (diag) {
                    const int qr = q0 + quad * 4 + reg;
                    const int key = kk0 + nt * 16 + l16;
                    v = (key > qr) ? -1e30f : v;
                }
                const float p = __expf(fminf(v, 30.f));
                s[nt][reg] = p;
                psum[reg] += p;
            }

        // P: C-layout -> LDS (stride 76) -> A-layout, per-wave region
#pragma unroll
        for (int nt = 0; nt < 4; ++nt)
#pragma unroll
            for (int reg = 0; reg < 4; ++reg)
                sPw[(quad * 4 + reg) * 76 + nt * 16 + l16] = (bf16)s[nt][reg];
        __asm__ volatile("s_waitcnt lgkmcnt(0)" ::: "memory");

        // psum butterfly over the 16-lane row group (independent of PV)
#pragma unroll
        for (int off = 1; off < 16; off <<= 1)
#pragma unroll
            for (int reg = 0; reg < 4; ++reg)
                psum[reg] += __shfl_xor(psum[reg], off, 64);
#pragma unroll
        for (int reg = 0; reg < 4; ++reg) lrow[reg] += psum[reg];

        const bf16x8 aP0 = *(const bf16x8*)(sPw + l16 * 76 + quad * 8);
        const bf16x8 aP1 = *(const bf16x8*)(sPw + l16 * 76 + 32 + quad * 8);
#pragma unroll
        for (int dd = 0; dd < 6; ++dd) {
            const bf16* vp = sV + (dd * 16 + l16) * 72 + quad * 8;
            const bf16x8 v0 = *(const bf16x8*)(vp);
            const bf16x8 v1 = *(const bf16x8*)(vp + 32);
            o[dd] = __builtin_amdgcn_mfma_f32_16x16x32_bf16(aP0, v0, o[dd], 0, 0, 0);
            o[dd] = __builtin_amdgcn_mfma_f32_16x16x32_bf16(aP1, v1, o[dd], 0, 0, 0);
        }
    };

    issue_tile(0);  // tile-0 loads in flight (only exposed wait of the block)

    for (int kb = 0; kb <= qBi; ++kb) {
        const int kk0 = kb * 64;

        bar_nodrain();  // prior tile's sK/sV reads done (no vmcnt drain!)

        // ---- write prefetched K tile: sK[key][d] (rows padded to 104) ----
#pragma unroll
        for (int c = 0; c < 3; ++c)
            *(bf16x8*)(sK + kKey[c] * 104 + kCh[c] * 8) = kreg[c];
        // ---- write prefetched V tile: sV[d][key] (packed b32) ----
#pragma unroll
        for (int c = 0; c < 3; ++c) {
#pragma unroll
            for (int jj = 0; jj < 4; ++jj) {
                bf16x2 pk; pk[0] = va[c][jj]; pk[1] = vb[c][jj];
                *(bf16x2*)(sV + (vDq[c] * 4 + jj) * 72 + vKey2[c]) = pk;
            }
        }

        // issue next tile's global loads AFTER the LDS writes consumed the
        // old register values; they ride across the barrier (vmcnt never
        // drained) and land during the compute phase below.
        if (kb < qBi) issue_tile(kk0 + 64);

        __asm__ volatile("s_waitcnt lgkmcnt(0)" ::: "memory");  // ds_writes visible
        bar_nodrain();

        // qB every tile; qA while kb <= qAi (both block-uniform)
        process(aQB0, aQB1, aQB2, oB, lB, q0B, kk0, kb == qBi);
        if (kb <= qAi)
            process(aQA0, aQA1, aQA2, oA, lA, q0A, kk0, kb == qAi);
    }

    // ---- write both outputs: aout[b, t, h*96 + d] ----
    bf16* opA = aout + (size_t)(b * T + q0A + quad * 4) * CC + h * HD + l16;
    bf16* opB = aout + (size_t)(b * T + q0B + quad * 4) * CC + h * HD + l16;
#pragma unroll
    for (int reg = 0; reg < 4; ++reg) {
        const float invA = 1.f / lA[reg];
        const float invB = 1.f / lB[reg];
#pragma unroll
        for (int dd = 0; dd < 6; ++dd) {
            opA[(size_t)reg * CC + dd * 16] = (bf16)(oA[dd][reg] * invA);
            opB[(size_t)reg * CC + dd * 16] = (bf16)(oB[dd][reg] * invB);
        }
    }
}

// ===========================================================================
extern "C" void kernel_launch(void* const* d_in, const int* in_sizes, int n_in,
                              void* d_out, int out_size, void* d_ws, size_t ws_size,
                              hipStream_t stream)
{
    const float* x      = (const float*)d_in[0];
    const float* ln1_g  = (const float*)d_in[1];
    const float* ln1_b  = (const float*)d_in[2];
    const float* attn_w = (const float*)d_in[3];
    const float* attn_b = (const float*)d_in[4];
    const float* proj_w = (const float*)d_in[5];
    const float* proj_b = (const float*)d_in[6];
    const float* ln2_g  = (const float*)d_in[7];
    const float* ln2_b  = (const float*)d_in[8];
    const float* fc_w   = (const float*)d_in[9];
    const float* fc_b   = (const float*)d_in[10];
    const float* fc2_w  = (const float*)d_in[11];
    const float* fc2_b  = (const float*)d_in[12];

    char* ws = (char*)d_ws;
    bf16*  attn_wT = (bf16*)(ws + 0);
    bf16*  proj_wT = (bf16*)(ws + 3538944);
    bf16*  fc_wT   = (bf16*)(ws + 4718592);
    bf16*  fc2_wT  = (bf16*)(ws + 9437184);
    bf16*  hbuf    = (bf16*)(ws + 14155776);   // h -> attn_out -> h2
    bf16*  qkv     = (bf16*)(ws + 39321600);   // dead after attention
    bf16*  x1      = (bf16*)(ws + 39321600);   // aliases dead qkv
    bf16*  act     = (bf16*)(ws + 64487424);   // [8192][3072] chunk buffer

    // all 4 weight transposes in ONE launch
    wtrans4<<<6912, dim3(32, 8), 0, stream>>>(attn_w, attn_wT, proj_w, proj_wT,
                                              fc_w, fc_wT, fc2_w, fc2_wT);

    // LN1: x (f32) -> h (bf16)
    ln_kernel<float><<<4096, 256, 0, stream>>>(x, ln1_g, ln1_b, hbuf);

    // QKV GEMM (grid = (M/128, N/TN); XCD = bm%8 groups A-panel readers)
    gemm_bt<0, 128><<<dim3(128, 18), 256, 0, stream>>>(
        hbuf, attn_wT, attn_b, nullptr, qkv, 16384, 2304, 768);

    // attention -> hbuf (attn_out); merged-pair causal, grid (bh, qA):
    // XCD = bh%8 so all q-blocks of one (b,h) share one XCD's L2.
    attn_kernel<<<dim3(128, 8), 256, 0, stream>>>(qkv, hbuf);

    // proj + residual: x1 (bf16, aliases dead qkv) = attn_out @ proj_w + b + x
    gemm_bt<1, 128><<<dim3(128, 6), 256, 0, stream>>>(
        hbuf, proj_wT, proj_b, x, x1, 16384, 768, 768);

    // LN2: x1 (bf16) -> h2 (bf16, in hbuf)
    ln_kernel<bf16><<<4096, 256, 0, stream>>>(x1, ln2_g, ln2_b, hbuf);

    // MLP in 2 chunks of 8192 rows; fc2 uses TN=64
    for (int c = 0; c < 2; ++c) {
        const size_t ro = (size_t)c * 8192;
        gemm_bt<2, 128><<<dim3(64, 24), 256, 0, stream>>>(
            hbuf + ro * 768, fc_wT, fc_b, nullptr, act, 8192, 3072, 768);
        gemm_bt<3, 64><<<dim3(64, 12), 256, 0, stream>>>(
            act, fc2_wT, fc2_b, x1 + ro * 768,
            (float*)d_out + ro * 768, 8192, 768, 3072);
    }
}